// Round 20
// baseline (58.667 us; speedup 1.0000x reference)
//
#include <hip/hip_runtime.h>

// Problem constants (match reference)
#define BB   8
#define CC   1024
#define TT   4096
#define HH   16
#define KK   31

#define NT    256               // threads per block (4 independent waves)
#define RPT   8                 // outputs per thread
#define NRD   10                // ds_read_b128 per thread window (40 floats)
#define WCH   136               // 16B chunks per wave buffer: 4 halo + 128 + 4 halo
#define SEGW  512               // outputs per wave-segment
#define HALF  2048              // outputs per block (4 waves * 512)

typedef float floatx4 __attribute__((ext_vector_type(4)));
typedef const float __attribute__((address_space(1)))* gptr_t;   // global
typedef float __attribute__((address_space(3)))* lptr_t;         // LDS

// Involution swizzle p = q ^ ((q>>3)&7): bijective on [0,136) (q>=128 fixed).
// Wave-logical chunk q holds x[seg0 - 16 + 4q .. +3] (sources clamped at true
// row edges; garbage patched in registers). Read pattern q = 2*l + c: per
// 16-lane phase each bank-quad is hit 2x (enumerated) ~ the wave64 floor.
__device__ __forceinline__ int swz(int q) { return q ^ ((q >> 3) & 7); }

// --- single fused kernel: block = (batch, 8-channel group, half-row); each of
//     the 4 waves owns a 512-output sub-segment with a PRIVATE double buffer.
//     8 channel iterations, depth-2 DMA prefetch, counted vmcnt, 0 barriers.
//     NEW vs r19: input DMA carries the NT (non-temporal) cache-policy bit ->
//     input lines are evict-first in L2/L3, letting the 132 MB output stream
//     stay L3-resident across graph replays (write traffic absorbed by L3). ---
// out[t] = bias + sum_k softmax(w)[k] * x[t + k - 15]
__global__ __launch_bounds__(NT) void lwconv_main(const float* __restrict__ inp,
                                                  const float* __restrict__ weight,
                                                  const float* __restrict__ bias,
                                                  float* __restrict__ out) {
    __shared__ floatx4 buf[4][2][WCH];       // 17,408 B -> 8 blocks/CU (wave cap)

    const int blk   = blockIdx.x;            // b*256 + g*2 + half
    const int half  = blk & 1;
    const int g     = (blk >> 1) & 127;
    const int b     = blk >> 8;
    const int c0    = g << 3;                // 8 consecutive channels, same head
    const int head  = c0 >> 6;
    const int tid   = threadIdx.x;
    const int wv    = tid >> 6;              // wave 0..3
    const int l     = tid & 63;              // lane

    const int seg0 = half * HALF + wv * SEGW;      // this wave's first output t

    const float* base  = inp + ((size_t)b * CC + c0) * TT;
    float*       obase = out + ((size_t)b * CC + c0) * TT;

    // stage channel i's wave-segment into buf[wv][i&1]: exactly 3 exec-uniform
    // DMA; chunks [0,64)+[64,128)+[72,136) (overlap = same bytes, benign).
    // aux=2 -> NT bit: read-once stream, evict-first in L2/L3.
    auto stage = [&](int i) {
        const float* rp = base + (size_t)i * TT;
        floatx4* wbuf = &buf[wv][i & 1][0];
        #pragma unroll
        for (int j = 0; j < 3; ++j) {
            const int p = (j == 2) ? (72 + l) : (j * 64 + l);   // physical chunk
            int f = seg0 - 16 + 4 * swz(p);                     // source float
            f = min(max(f, 0), TT - 4);                         // clamp row edges
            __builtin_amdgcn_global_load_lds((gptr_t)(rp + f),
                                             (lptr_t)(&wbuf[p]), 16, 0, 2);
        }
    };

    stage(0);
    stage(1);

    // ---- fused softmax of this head's 31 taps (redundant per block; hides
    //      under the prologue DMA latency) -> readfirstlane pins to SGPRs ----
    float w[KK];
    {
        const float* wh = weight + head * KK;   // uniform -> s_loads
        float m = -1e30f;
        #pragma unroll
        for (int k = 0; k < KK; ++k) { w[k] = wh[k]; m = fmaxf(m, w[k]); }
        float s = 0.f;
        #pragma unroll
        for (int k = 0; k < KK; ++k) { w[k] = expf(w[k] - m); s += w[k]; }
        const float inv = 1.f / s;
        #pragma unroll
        for (int k = 0; k < KK; ++k)
            w[k] = __int_as_float(__builtin_amdgcn_readfirstlane(
                       __float_as_int(w[k] * inv)));
    }
    const float bval = bias[head];

    #pragma unroll 1
    for (int r = 0; r < BB; ++r) {
        // Counted wait for row r's 3 DMA (per-wave in-order retirement).
        // Issue order/iter: [3 DMA][2 stores]. Newer than DMA_r at wait:
        // r=0 -> DMA_1(3); r=1 -> DMA_2(3)+st_0(2)=5;
        // steady -> st_{r-2}(2)+DMA_{r+1}(3)+st_{r-1}(2)=7; r=7 -> 4.
        if (r == 0)
            asm volatile("s_waitcnt vmcnt(3)" ::: "memory");
        else if (r == 1)
            asm volatile("s_waitcnt vmcnt(5)" ::: "memory");
        else if (r == BB - 1)
            asm volatile("s_waitcnt vmcnt(4)" ::: "memory");
        else
            asm volatile("s_waitcnt vmcnt(7)" ::: "memory");
        __builtin_amdgcn_sched_barrier(0);

        // window: 10 ds_read_b128 from this wave's buffer. NO explicit lgkm
        // drain here: the compiler emits fine-grained lgkmcnt(N) inside the
        // FMA block, overlapping LDS latency with compute.
        float xv[4 * NRD];
        #pragma unroll
        for (int c = 0; c < NRD; ++c) {
            floatx4 v = buf[wv][r & 1][swz(2 * l + c)];
            #pragma unroll
            for (int e = 0; e < 4; ++e) xv[4 * c + e] = v[e];
        }

        // register patch of row-edge padding (garbage from clamped DMA).
        // xv[e] = x[seg0 + 8*l - 16 + e]; zero iff global index <0 or >=4096.
        if (half == 0) {
            if (tid < 2) {
                #pragma unroll
                for (int e = 0; e < 16; ++e)
                    xv[e] = (e < 16 - 8 * tid) ? 0.f : xv[e];
            }
        } else {
            if (tid >= NT - 2) {
                #pragma unroll
                for (int e = 24; e < 40; ++e)
                    xv[e] = (e >= 2064 - 8 * tid) ? 0.f : xv[e];
            }
        }

        // compute channel r's 8 outputs
        float acc[RPT];
        #pragma unroll
        for (int p = 0; p < RPT; ++p) acc[p] = bval;
        #pragma unroll
        for (int k = 0; k < KK; ++k) {
            #pragma unroll
            for (int p = 0; p < RPT; ++p)
                acc[p] = fmaf(xv[p + 1 + k], w[k], acc[p]);
        }

        // drain my LDS reads (free: FMA consumed them all), THEN overwrite
        // my buffer with row r+2's DMA; stores last (keeps vmcnt schedule).
        asm volatile("s_waitcnt lgkmcnt(0)" ::: "memory");
        __builtin_amdgcn_sched_barrier(0);
        if (r + 2 < BB) stage(r + 2);
        __builtin_amdgcn_sched_barrier(0);

        float* orow = obase + (size_t)r * TT + seg0 + (l << 3);
        #pragma unroll
        for (int c2 = 0; c2 < RPT / 4; ++c2) {
            floatx4 o = { acc[4 * c2], acc[4 * c2 + 1],
                          acc[4 * c2 + 2], acc[4 * c2 + 3] };
            *reinterpret_cast<floatx4*>(orow + 4 * c2) = o;
        }
    }
}

extern "C" void kernel_launch(void* const* d_in, const int* in_sizes, int n_in,
                              void* d_out, int out_size, void* d_ws, size_t ws_size,
                              hipStream_t stream) {
    const float* inp    = (const float*)d_in[0];   // (B, C, T) fp32
    const float* weight = (const float*)d_in[1];   // (H, 1, K) fp32
    const float* bias   = (const float*)d_in[2];   // (H,) fp32
    float* out = (float*)d_out;

    const int blocks = BB * (CC / 8) * 2;          // 2048 = 8 blocks/CU exactly
    lwconv_main<<<blocks, NT, 0, stream>>>(inp, weight, bias, out);
}

// Round 21
// 49.161 us; speedup vs baseline: 1.1934x; 1.1934x over previous
//
#include <hip/hip_runtime.h>

// Problem constants (match reference)
#define BB   8
#define CC   1024
#define TT   4096
#define HH   16
#define KK   31

#define NT    256               // threads per block (4 independent waves)
#define RPT   8                 // outputs per thread
#define NRD   10                // ds_read_b128 per thread window (40 floats)
#define WCH   136               // 16B chunks per wave buffer: 4 halo + 128 + 4 halo
#define SEGW  512               // outputs per wave-segment
#define HALF  2048              // outputs per block (4 waves * 512)

typedef float floatx4 __attribute__((ext_vector_type(4)));
typedef const float __attribute__((address_space(1)))* gptr_t;   // global
typedef float __attribute__((address_space(3)))* lptr_t;         // LDS

// Involution swizzle p = q ^ ((q>>3)&7): bijective on [0,136) (q>=128 fixed).
// Wave-logical chunk q holds x[seg0 - 16 + 4q .. +3] (sources clamped at true
// row edges; garbage patched in registers). Read pattern q = 2*l + c: per
// 16-lane phase each bank-quad is hit 2x (enumerated) ~ the wave64 floor.
__device__ __forceinline__ int swz(int q) { return q ^ ((q >> 3) & 7); }

// --- single fused kernel: block = (batch, 8-channel group, half-row); each of
//     the 4 waves owns a 512-output sub-segment with a PRIVATE double buffer.
//     8 channel iterations, depth-2 DMA prefetch, counted vmcnt, 0 barriers.
//     vs r19: (1) stores issue BEFORE the lgkm drain + prefetch DMA (earlier
//     entry into the store queue; vmcnt re-derived -> 3/5/5/2); (2) XCD-
//     bijective blockIdx swizzle co-locates halo-sharing neighbor blocks on
//     one XCD L2. Input DMA back to default cache policy (r20 NT regressed).
// out[t] = bias + sum_k softmax(w)[k] * x[t + k - 15]
__global__ __launch_bounds__(NT) void lwconv_main(const float* __restrict__ inp,
                                                  const float* __restrict__ weight,
                                                  const float* __restrict__ bias,
                                                  float* __restrict__ out) {
    __shared__ floatx4 buf[4][2][WCH];       // 17,408 B -> 8 blocks/CU (wave cap)

    // XCD-bijective swizzle: 2048 blocks, 8 XCDs, 2048%8==0 -> nb = xcd*256+slot.
    // Consecutive ORIGINAL ids (halo-sharing neighbors) land on the same XCD.
    const int blk   = ((blockIdx.x & 7) << 8) | (blockIdx.x >> 3);
    const int half  = blk & 1;
    const int g     = (blk >> 1) & 127;
    const int b     = blk >> 8;
    const int c0    = g << 3;                // 8 consecutive channels, same head
    const int head  = c0 >> 6;
    const int tid   = threadIdx.x;
    const int wv    = tid >> 6;              // wave 0..3
    const int l     = tid & 63;              // lane

    const int seg0 = half * HALF + wv * SEGW;      // this wave's first output t

    const float* base  = inp + ((size_t)b * CC + c0) * TT;
    float*       obase = out + ((size_t)b * CC + c0) * TT;

    // stage channel i's wave-segment into buf[wv][i&1]: exactly 3 exec-uniform
    // DMA; chunks [0,64)+[64,128)+[72,136) (overlap = same bytes, benign).
    auto stage = [&](int i) {
        const float* rp = base + (size_t)i * TT;
        floatx4* wbuf = &buf[wv][i & 1][0];
        #pragma unroll
        for (int j = 0; j < 3; ++j) {
            const int p = (j == 2) ? (72 + l) : (j * 64 + l);   // physical chunk
            int f = seg0 - 16 + 4 * swz(p);                     // source float
            f = min(max(f, 0), TT - 4);                         // clamp row edges
            __builtin_amdgcn_global_load_lds((gptr_t)(rp + f),
                                             (lptr_t)(&wbuf[p]), 16, 0, 0);
        }
    };

    stage(0);
    stage(1);

    // ---- fused softmax of this head's 31 taps (redundant per block; hides
    //      under the prologue DMA latency) -> readfirstlane pins to SGPRs ----
    float w[KK];
    {
        const float* wh = weight + head * KK;   // uniform -> s_loads
        float m = -1e30f;
        #pragma unroll
        for (int k = 0; k < KK; ++k) { w[k] = wh[k]; m = fmaxf(m, w[k]); }
        float s = 0.f;
        #pragma unroll
        for (int k = 0; k < KK; ++k) { w[k] = expf(w[k] - m); s += w[k]; }
        const float inv = 1.f / s;
        #pragma unroll
        for (int k = 0; k < KK; ++k)
            w[k] = __int_as_float(__builtin_amdgcn_readfirstlane(
                       __float_as_int(w[k] * inv)));
    }
    const float bval = bias[head];

    #pragma unroll 1
    for (int r = 0; r < BB; ++r) {
        // Counted wait for row r's 3 DMA (per-wave in-order retirement).
        // Issue order/iter: [2 stores][3 DMA]. Newer than DMA_r at wait:
        // r=0 -> DMA_1(3); r=1 -> st_0(2)+DMA_2(3)=5;
        // steady -> st_{r-1}(2)+DMA_{r+1}(3)=5; r=7 -> st_6(2)=2.
        if (r == 0)
            asm volatile("s_waitcnt vmcnt(3)" ::: "memory");
        else if (r == BB - 1)
            asm volatile("s_waitcnt vmcnt(2)" ::: "memory");
        else
            asm volatile("s_waitcnt vmcnt(5)" ::: "memory");
        __builtin_amdgcn_sched_barrier(0);

        // window: 10 ds_read_b128 from this wave's buffer. NO explicit lgkm
        // drain here: the compiler emits fine-grained lgkmcnt(N) inside the
        // FMA block, overlapping LDS latency with compute.
        float xv[4 * NRD];
        #pragma unroll
        for (int c = 0; c < NRD; ++c) {
            floatx4 v = buf[wv][r & 1][swz(2 * l + c)];
            #pragma unroll
            for (int e = 0; e < 4; ++e) xv[4 * c + e] = v[e];
        }

        // register patch of row-edge padding (garbage from clamped DMA).
        // xv[e] = x[seg0 + 8*l - 16 + e]; zero iff global index <0 or >=4096.
        if (half == 0) {
            if (tid < 2) {
                #pragma unroll
                for (int e = 0; e < 16; ++e)
                    xv[e] = (e < 16 - 8 * tid) ? 0.f : xv[e];
            }
        } else {
            if (tid >= NT - 2) {
                #pragma unroll
                for (int e = 24; e < 40; ++e)
                    xv[e] = (e >= 2064 - 8 * tid) ? 0.f : xv[e];
            }
        }

        // compute channel r's 8 outputs
        float acc[RPT];
        #pragma unroll
        for (int p = 0; p < RPT; ++p) acc[p] = bval;
        #pragma unroll
        for (int k = 0; k < KK; ++k) {
            #pragma unroll
            for (int p = 0; p < RPT; ++p)
                acc[p] = fmaf(xv[p + 1 + k], w[k], acc[p]);
        }

        // stores FIRST (depend only on FMAs -> enter the memory queue early)
        float* orow = obase + (size_t)r * TT + seg0 + (l << 3);
        #pragma unroll
        for (int c2 = 0; c2 < RPT / 4; ++c2) {
            floatx4 o = { acc[4 * c2], acc[4 * c2 + 1],
                          acc[4 * c2 + 2], acc[4 * c2 + 3] };
            *reinterpret_cast<floatx4*>(orow + 4 * c2) = o;
        }
        __builtin_amdgcn_sched_barrier(0);

        // drain my LDS reads (free: FMA consumed them all), THEN overwrite
        // my buffer with row r+2's DMA.
        asm volatile("s_waitcnt lgkmcnt(0)" ::: "memory");
        __builtin_amdgcn_sched_barrier(0);
        if (r + 2 < BB) stage(r + 2);
        __builtin_amdgcn_sched_barrier(0);
    }
}

extern "C" void kernel_launch(void* const* d_in, const int* in_sizes, int n_in,
                              void* d_out, int out_size, void* d_ws, size_t ws_size,
                              hipStream_t stream) {
    const float* inp    = (const float*)d_in[0];   // (B, C, T) fp32
    const float* weight = (const float*)d_in[1];   // (H, 1, K) fp32
    const float* bias   = (const float*)d_in[2];   // (H,) fp32
    float* out = (float*)d_out;

    const int blocks = BB * (CC / 8) * 2;          // 2048 = 8 blocks/CU exactly
    lwconv_main<<<blocks, NT, 0, stream>>>(inp, weight, bias, out);
}